// Round 6
// baseline (550.693 us; speedup 1.0000x reference)
//
#include <hip/hip_runtime.h>
#include <hip/hip_bf16.h>

#define NN 50000
#define NE 800000
#define FD 256
#define LD 128
#define BN_EPS 1e-5f
#define NHW 12504  // half-wave row groups in spmm (NN/4 rounded to x8)

typedef __bf16 bf16_t;
typedef bf16_t bf16x8 __attribute__((ext_vector_type(8)));
typedef float f32x4 __attribute__((ext_vector_type(4)));

// ---------------- CSR build ----------------

__global__ __launch_bounds__(256) void k_count(const int* __restrict__ dst,
                                               int* __restrict__ cnt) {
  int i = blockIdx.x * blockDim.x + threadIdx.x;
  if (i < NE) atomicAdd(&cnt[dst[i]], 1);
}

__global__ __launch_bounds__(256) void k_scanA(const int* __restrict__ cnt,
                                               int* __restrict__ row_ptr,
                                               int* __restrict__ partials) {
  __shared__ int ws[4];
  int b = blockIdx.x, t = threadIdx.x;
  int base = b * 1024 + t * 4;
  int vals[4];
#pragma unroll
  for (int j = 0; j < 4; ++j) vals[j] = (base + j < NN) ? cnt[base + j] : 0;
  int tsum = vals[0] + vals[1] + vals[2] + vals[3];
  int lane = t & 63, wid = t >> 6;
  int x = tsum;
#pragma unroll
  for (int off = 1; off < 64; off <<= 1) {
    int y = __shfl_up(x, off, 64);
    if (lane >= off) x += y;
  }
  if (lane == 63) ws[wid] = x;
  __syncthreads();
  int woff = 0;
  for (int w = 0; w < wid; ++w) woff += ws[w];
  int run = woff + x - tsum;
#pragma unroll
  for (int j = 0; j < 4; ++j) {
    if (base + j < NN) row_ptr[base + j] = run;
    run += vals[j];
  }
  if (t == 255) partials[b] = woff + x;
}

__global__ void k_scanB(int* __restrict__ partials, int* __restrict__ row_ptr,
                        int nblk) {
  int lane = threadIdx.x;
  int v = (lane < nblk) ? partials[lane] : 0;
  int x = v;
#pragma unroll
  for (int off = 1; off < 64; off <<= 1) {
    int y = __shfl_up(x, off, 64);
    if (lane >= off) x += y;
  }
  if (lane < nblk) partials[lane] = x - v;
  if (lane == 0) row_ptr[NN] = NE;
}

__global__ __launch_bounds__(256) void k_scanC(int* __restrict__ row_ptr,
                                               const int* __restrict__ partials,
                                               const int* __restrict__ cnt,
                                               float* __restrict__ dinv) {
  int b = blockIdx.x;
  int off = partials[b];
  int base = b * 1024 + threadIdx.x * 4;
#pragma unroll
  for (int j = 0; j < 4; ++j)
    if (base + j < NN) {
      row_ptr[base + j] += off;
      dinv[base + j] = rsqrtf(1.0f + (float)cnt[base + j]);
    }
}

__global__ __launch_bounds__(256) void k_fill(const int* __restrict__ src,
                                              const int* __restrict__ dst,
                                              const int* __restrict__ row_ptr,
                                              int* __restrict__ cursor,
                                              int* __restrict__ col) {
  int i = blockIdx.x * blockDim.x + threadIdx.x;
  if (i < NE) {
    int d = dst[i];
    int p = atomicAdd(&cursor[d], 1);
    col[row_ptr[d] + p] = src[i];
  }
}

// ---------------- weight convert to MFMA-fragment-swizzled bf16 ------------
__global__ __launch_bounds__(256) void k_convw(
    const float* __restrict__ W0, const float* __restrict__ W1,
    const float* __restrict__ Wmu, const float* __restrict__ bmu,
    const float* __restrict__ Wlv, const float* __restrict__ blv,
    bf16_t* __restrict__ W0s, bf16_t* __restrict__ W1s,
    bf16_t* __restrict__ Whs, float* __restrict__ biash) {
  int k = blockIdx.x, n = threadIdx.x;
  int chunk = (n >> 4) * 8 + (k >> 5);
  int slot = ((k >> 3) & 3) * 16 + (n & 15);
  int idx = chunk * 512 + slot * 8 + (k & 7);
  W0s[idx] = (bf16_t)W0[k * 256 + n];
  W1s[idx] = (bf16_t)W1[k * 256 + n];
  float wh = (n < 128) ? Wmu[k * 128 + n] : Wlv[k * 128 + (n - 128)];
  Whs[idx] = (bf16_t)wh;
  if (k == 0) biash[n] = (n < 128) ? bmu[n] : blv[n - 128];
}

// ---------------- barrier-free MFMA GEMM ----------------
// bf16 A is feature-sliced [8][M][32]; fp32 A (layer 0 input x) row-major.
// bf16 C written sliced; fp32 C (heads) row-major split.
__global__ __launch_bounds__(256) void k_mgemm(
    const void* __restrict__ Ap, int a_f32, const bf16_t* __restrict__ Wswz,
    bf16_t* __restrict__ Cb, float* __restrict__ Cf, int M,
    const float* __restrict__ bn_scale, const float* __restrict__ bn_shift,
    const float* __restrict__ row_scale, const float* __restrict__ col_bias,
    int split) {
  __shared__ bf16_t Ws[64 * 512];  // 64 chunks x 1 KB
  const int tid = threadIdx.x;
  const int half = blockIdx.y;
  const int wave = tid >> 6, lane = tid & 63;
  const int m = lane & 15, q = lane >> 4;  // A-frag: row m, k-octet q
  const int row0 = blockIdx.x * 128 + wave * 32;
  const int rg0 = row0 + m, rg1 = row0 + 16 + m;
  const int rc0 = rg0 < M ? rg0 : M - 1;
  const int rc1 = rg1 < M ? rg1 : M - 1;

  // bf16 path: issue all A-loads BEFORE W staging (latency overlap)
  bf16x8 rawA[16];
  if (!a_f32) {
    const bf16_t* As = (const bf16_t*)Ap;
#pragma unroll
    for (int kb = 0; kb < 8; ++kb) {
      rawA[kb * 2 + 0] =
          *(const bf16x8*)&As[((size_t)kb * M + rc0) * 32 + q * 8];
      rawA[kb * 2 + 1] =
          *(const bf16x8*)&As[((size_t)kb * M + rc1) * 32 + q * 8];
    }
  }

  {
    const bf16_t* srcW = Wswz + (size_t)half * 64 * 512;
    bf16x8 wraw[16];
#pragma unroll
    for (int i = 0; i < 16; ++i)
      wraw[i] = *(const bf16x8*)&srcW[(i * 256 + tid) * 8];
#pragma unroll
    for (int i = 0; i < 16; ++i) *(bf16x8*)&Ws[(i * 256 + tid) * 8] = wraw[i];
  }
  __syncthreads();

  bf16x8 af[2][8];
  if (a_f32) {
    const float* p0 = (const float*)Ap + (size_t)rc0 * 256 + q * 8;
    const float* p1 = (const float*)Ap + (size_t)rc1 * 256 + q * 8;
#pragma unroll
    for (int g = 0; g < 2; ++g) {
      const float* p = g ? p1 : p0;
      float4 f0[8], f1[8];
#pragma unroll
      for (int kb = 0; kb < 8; ++kb) {
        f0[kb] = *(const float4*)(p + kb * 32);
        f1[kb] = *(const float4*)(p + kb * 32 + 4);
      }
#pragma unroll
      for (int kb = 0; kb < 8; ++kb) {
        bf16x8 fr;
        fr[0] = (bf16_t)f0[kb].x; fr[1] = (bf16_t)f0[kb].y;
        fr[2] = (bf16_t)f0[kb].z; fr[3] = (bf16_t)f0[kb].w;
        fr[4] = (bf16_t)f1[kb].x; fr[5] = (bf16_t)f1[kb].y;
        fr[6] = (bf16_t)f1[kb].z; fr[7] = (bf16_t)f1[kb].w;
        af[g][kb] = fr;
      }
    }
  } else {
#pragma unroll
    for (int kb = 0; kb < 8; ++kb) {
      float s[8], h[8];
      if (bn_scale) {
        float4 s0 = *(const float4*)&bn_scale[kb * 32 + q * 8];
        float4 s1 = *(const float4*)&bn_scale[kb * 32 + q * 8 + 4];
        float4 h0 = *(const float4*)&bn_shift[kb * 32 + q * 8];
        float4 h1 = *(const float4*)&bn_shift[kb * 32 + q * 8 + 4];
        s[0] = s0.x; s[1] = s0.y; s[2] = s0.z; s[3] = s0.w;
        s[4] = s1.x; s[5] = s1.y; s[6] = s1.z; s[7] = s1.w;
        h[0] = h0.x; h[1] = h0.y; h[2] = h0.z; h[3] = h0.w;
        h[4] = h1.x; h[5] = h1.y; h[6] = h1.z; h[7] = h1.w;
      }
#pragma unroll
      for (int g = 0; g < 2; ++g) {
        bf16x8 r = rawA[kb * 2 + g];
        bf16x8 fr;
#pragma unroll
        for (int j = 0; j < 8; ++j) {
          float v = (float)r[j];
          if (bn_scale) v = fmaxf(fmaf(v, s[j], h[j]), 0.f);
          fr[j] = (bf16_t)v;
        }
        af[g][kb] = fr;
      }
    }
  }

  f32x4 acc[2][8] = {};
#pragma unroll
  for (int nt = 0; nt < 8; ++nt) {
#pragma unroll
    for (int kb = 0; kb < 8; ++kb) {
      bf16x8 b = *(const bf16x8*)&Ws[(nt * 8 + kb) * 512 + lane * 8];
      acc[0][nt] = __builtin_amdgcn_mfma_f32_16x16x32_bf16(af[0][kb], b,
                                                           acc[0][nt], 0, 0, 0);
      acc[1][nt] = __builtin_amdgcn_mfma_f32_16x16x32_bf16(af[1][kb], b,
                                                           acc[1][nt], 0, 0, 0);
    }
  }

  // epilogue: D row_local = q*4 + r, col_local = m  [m89-verified layout]
#pragma unroll
  for (int g = 0; g < 2; ++g) {
#pragma unroll
    for (int r = 0; r < 4; ++r) {
      int row = row0 + g * 16 + q * 4 + r;
      if (row >= M) continue;
      float rs = row_scale ? row_scale[row] : 1.0f;
#pragma unroll
      for (int nt = 0; nt < 8; ++nt) {
        int col = half * 128 + nt * 16 + m;
        float v = acc[g][nt][r] * rs;
        if (col_bias) v += col_bias[col];
        if (Cb) {
          // sliced write: [slice][row][within]
          Cb[((size_t)(col >> 5) * M + row) * 32 + (col & 31)] = (bf16_t)v;
        } else if (!split) {
          Cf[(size_t)row * 256 + col] = v;
        } else {
          if (col < 128)
            Cf[(size_t)row * 128 + col] = v;
          else
            Cf[(size_t)(M + row) * 128 + (col - 128)] = v;
        }
      }
    }
  }
}

// ---------------- XCD-sliced SpMM + fused BN stats ----------------
// g/out feature-sliced [8][NN][32] bf16; block handles slice blockIdx.x
// (consecutive blockIdx.x round-robins across XCDs -> slice working set
// 3.2 MB fits per-XCD L2). Half-wave per row; 4 lanes per neighbor (64 B
// slice), 8 neighbors/iter; 3-step butterfly reduce; 4 strided rows/half-wave.
__global__ __launch_bounds__(256) void k_spmm(const bf16_t* __restrict__ g,
                                              const int* __restrict__ row_ptr,
                                              const int* __restrict__ col,
                                              const float* __restrict__ dinv,
                                              bf16_t* __restrict__ out,
                                              float* __restrict__ stats) {
  __shared__ float sbuf[8][64];
  const int slice = blockIdx.x;       // 0..7
  const int hw = threadIdx.x >> 5;    // 0..7
  const int sl = threadIdx.x & 31;
  const int fsub = (sl & 3) * 8;      // feature offset within slice
  const int nsub = sl >> 2;           // neighbor sub-slot 0..7
  const bf16_t* gs = g + (size_t)slice * NN * 32;
  bf16_t* os = out + (size_t)slice * NN * 32;
  float s[8] = {}, s2[8] = {};
  const int H = blockIdx.y * 8 + hw;
#pragma unroll 1
  for (int jr = 0; jr < 4; ++jr) {
    int dst = H + NHW * jr;
    if (dst >= NN) break;
    int s0 = row_ptr[dst], e = row_ptr[dst + 1];
    float a[8] = {};
#pragma unroll 1
    for (int b0 = s0; b0 < e; b0 += 32) {
      int nn = e - b0;
      if (nn > 32) nn = 32;
      int c = (b0 + sl < e) ? col[b0 + sl] : 0;
#pragma unroll
      for (int i = 0; i < 32; i += 8) {
        if (i >= nn) break;  // uniform across half-wave
        int idx = i + nsub;
        int srcn = __shfl(c, idx, 32);
        bf16x8 v = *(const bf16x8*)&gs[(size_t)srcn * 32 + fsub];
        float w = (idx < nn) ? 1.0f : 0.0f;
#pragma unroll
        for (int j = 0; j < 8; ++j) a[j] = fmaf(w, (float)v[j], a[j]);
      }
    }
    // butterfly reduce across the 8 neighbor sub-slots (within half-wave)
#pragma unroll
    for (int msk = 4; msk <= 16; msk <<= 1)
#pragma unroll
      for (int j = 0; j < 8; ++j) a[j] += __shfl_xor(a[j], msk, 32);
    if (sl < 4) {
      bf16x8 sv = *(const bf16x8*)&gs[(size_t)dst * 32 + fsub];
      float dv = dinv[dst];
      bf16x8 ov;
#pragma unroll
      for (int j = 0; j < 8; ++j) {
        float t = (a[j] + (float)sv[j]) * dv;
        ov[j] = (bf16_t)t;
        float qv = (float)ov[j];
        s[j] += qv;
        s2[j] = fmaf(qv, qv, s2[j]);
      }
      *(bf16x8*)&os[(size_t)dst * 32 + fsub] = ov;
    }
  }
  if (sl < 4) {
#pragma unroll
    for (int j = 0; j < 8; ++j) {
      sbuf[hw][sl * 8 + j] = s[j];
      sbuf[hw][32 + sl * 8 + j] = s2[j];
    }
  }
  __syncthreads();
  int t = threadIdx.x;
  if (t < 64) {
    float tot = 0.f;
#pragma unroll
    for (int w = 0; w < 8; ++w) tot += sbuf[w][t];
    int f = slice * 32 + (t & 31);
    atomicAdd(&stats[(t < 32 ? 0 : 256) + f], tot);
  }
}

__global__ __launch_bounds__(256) void k_bnfinal(const float* __restrict__ stats,
                                                 const float* __restrict__ gamma,
                                                 const float* __restrict__ beta,
                                                 float* __restrict__ bnsc,
                                                 float* __restrict__ bnsh) {
  int t = threadIdx.x;
  float mean = stats[t] * (1.0f / NN);
  float var = stats[256 + t] * (1.0f / NN) - mean * mean;
  float rs = rsqrtf(var + BN_EPS);
  float sc = gamma[t] * rs;
  bnsc[t] = sc;
  bnsh[t] = beta[t] - mean * sc;
}

// ---------------- launch ----------------
extern "C" void kernel_launch(void* const* d_in, const int* in_sizes, int n_in,
                              void* d_out, int out_size, void* d_ws, size_t ws_size,
                              hipStream_t stream) {
  const float* x = (const float*)d_in[0];
  const int* ei = (const int*)d_in[1];
  const int* esrc = ei;
  const int* edst = ei + NE;
  const float* W0 = (const float*)d_in[2];
  const float* gamma0 = (const float*)d_in[4];
  const float* beta0 = (const float*)d_in[5];
  const float* W1 = (const float*)d_in[6];
  const float* gamma1 = (const float*)d_in[8];
  const float* beta1 = (const float*)d_in[9];
  const float* W_mu = (const float*)d_in[10];
  const float* b_mu = (const float*)d_in[11];
  const float* W_lv = (const float*)d_in[12];
  const float* b_lv = (const float*)d_in[13];
  float* out = (float*)d_out;

  // workspace carve: cnt|cursor|statsAll contiguous -> one memset
  bf16_t* g16 = (bf16_t*)d_ws;                        // [8][NN][32]
  bf16_t* agg16 = g16 + (size_t)NN * 256;             // [8][NN][32]
  int* cnt = (int*)(agg16 + (size_t)NN * 256);        // NN
  int* cursor = cnt + NN;                             // NN
  float* statsAll = (float*)(cursor + NN);            // 1024
  float* dinv = statsAll + 1024;                      // NN
  float* bnsc0 = dinv + NN;
  float* bnsh0 = bnsc0 + FD;
  float* bnsc1 = bnsh0 + FD;
  float* bnsh1 = bnsc1 + FD;
  float* biash = bnsh1 + FD;                          // 256
  bf16_t* W0s = (bf16_t*)(biash + 256);               // 65536 each
  bf16_t* W1s = W0s + 256 * 256;
  bf16_t* Whs = W1s + 256 * 256;
  int* row_ptr = (int*)(Whs + 256 * 256);             // NN+4
  int* col = row_ptr + NN + 4;                        // NE
  int* partials = col + NE;                           // 64

  const int SCAN_BLKS = (NN + 1023) / 1024;  // 49

  hipMemsetAsync(cnt, 0, (2 * NN + 1024) * sizeof(int), stream);
  k_count<<<(NE + 255) / 256, 256, 0, stream>>>(edst, cnt);
  k_scanA<<<SCAN_BLKS, 256, 0, stream>>>(cnt, row_ptr, partials);
  k_scanB<<<1, 64, 0, stream>>>(partials, row_ptr, SCAN_BLKS);
  k_scanC<<<SCAN_BLKS, 256, 0, stream>>>(row_ptr, partials, cnt, dinv);
  k_fill<<<(NE + 255) / 256, 256, 0, stream>>>(esrc, edst, row_ptr, cursor, col);
  k_convw<<<256, 256, 0, stream>>>(W0, W1, W_mu, b_mu, W_lv, b_lv, W0s, W1s,
                                   Whs, biash);

  dim3 gg((NN + 127) / 128, 2);
  dim3 gs2(8, NHW / 8);  // (slice, row-chunk): slice fastest -> XCD pinned

  // layer 0
  k_mgemm<<<gg, 256, 0, stream>>>(x, 1, W0s, g16, nullptr, NN, nullptr, nullptr,
                                  dinv, nullptr, 0);
  k_spmm<<<gs2, 256, 0, stream>>>(g16, row_ptr, col, dinv, agg16, statsAll);
  k_bnfinal<<<1, FD, 0, stream>>>(statsAll, gamma0, beta0, bnsc0, bnsh0);

  // layer 1
  k_mgemm<<<gg, 256, 0, stream>>>(agg16, 0, W1s, g16, nullptr, NN, bnsc0, bnsh0,
                                  dinv, nullptr, 0);
  k_spmm<<<gs2, 256, 0, stream>>>(g16, row_ptr, col, dinv, agg16,
                                  statsAll + 512);
  k_bnfinal<<<1, FD, 0, stream>>>(statsAll + 512, gamma1, beta1, bnsc1, bnsh1);

  // heads (fused mu|logvar)
  k_mgemm<<<gg, 256, 0, stream>>>(agg16, 0, Whs, nullptr, out, NN, bnsc1, bnsh1,
                                  nullptr, biash, 1);
}